// Round 8
// baseline (6192.350 us; speedup 1.0000x reference)
//
#include <hip/hip_runtime.h>

#define TT 512
#define BB 256
#define HH 512
#define FH 2048   // 4*H

typedef __attribute__((ext_vector_type(8))) short short8;
typedef __attribute__((ext_vector_type(4))) short short4v;
typedef __attribute__((ext_vector_type(4))) float f32x4;
typedef __attribute__((ext_vector_type(4))) unsigned uint4v;

__device__ __forceinline__ short f2bf(float f) {
  union { float f; unsigned u; } v; v.f = f;
  unsigned r = v.u + 0x7fffu + ((v.u >> 16) & 1u);   // RNE
  return (short)(r >> 16);
}

__device__ __forceinline__ float sigm(float x) {
  return 1.f / (1.f + __expf(-x));
}
__device__ __forceinline__ float tanh_fast(float x) {
  float e = __expf(2.f * x);
  return 1.f - 2.f / (e + 1.f);
}

// prep: weight transposes (bf16 col-major over K=512), X->bf16, packed h init,
// c init, counters zero, fallback h init.
__global__ void prep_kernel(const float* __restrict__ Wi, const float* __restrict__ Wh,
                            const float* __restrict__ h0, const float* __restrict__ c0,
                            const float* __restrict__ x,
                            short* __restrict__ WiT, short* __restrict__ WhT,
                            unsigned* __restrict__ hb0, float* __restrict__ cb,
                            short* __restrict__ hbf, short* __restrict__ Xb,
                            int* __restrict__ cnt) {
  int idx = blockIdx.x * blockDim.x + threadIdx.x;
  int stride = gridDim.x * blockDim.x;
  for (int i = idx; i < FH * HH; i += stride) {
    int col = i >> 9;
    int k = i & 511;
    WiT[i] = f2bf(Wi[(size_t)k * FH + col]);
    WhT[i] = f2bf(Wh[(size_t)k * FH + col]);
  }
  for (int i = idx; i < BB * HH; i += stride) {
    hbf[i] = f2bf(h0[i]);
    cb[i] = c0[i];
  }
  for (int i = idx; i < BB * 256; i += stride) {
    int row = i >> 8;
    int cpx = (i & 255) * 2;
    hb0[i] = (unsigned)(unsigned short)f2bf(h0[(size_t)row * HH + cpx]) |
             ((unsigned)(unsigned short)f2bf(h0[(size_t)row * HH + cpx + 1]) << 16);
  }
  for (int i = idx; i < 8 * TT; i += stride) cnt[i] = 0;
  const size_t nx4 = (size_t)TT * BB * HH / 4;
  for (size_t i = idx; i < nx4; i += stride) {
    f32x4 v = *(const f32x4*)(x + i * 4);
    short4v s = { f2bf(v[0]), f2bf(v[1]), f2bf(v[2]), f2bf(v[3]) };
    *(short4v*)(Xb + i * 4) = s;
  }
}

// Fused persistent kernel: 256 blocks = 8 groups x 32 col-groups, 128 threads
// (2 waves). Wave owns 16 rows x 16 h-cols x 4 gates. Per step:
//   X phase  : gates += x_t @ Wi  (Xb direct, WiT from L2) — runs BEFORE the
//              poll, filling the inter-block wait window.
//   poll     : single counter word per (group, t-1) == 32.
//   H phase  : h fragments loaded DIRECTLY from L3 (relaxed-atomic u32, reset-
//              masked in-register) -> MFMA with LDS-resident WhT slice.
//   epilogue : in-register (C layout row=kg*4+j, col=lc) — no LDS exchange.
//   publish  : packed u32 stores -> vmcnt(0) -> one barrier -> counter add;
//              ys/final stores after the add (off the critical path).
__global__ __launch_bounds__(128) void lstm_fused(
    const int* __restrict__ resets,     // (T,B)
    const short* __restrict__ WiT,      // (2048,512) bf16
    const short* __restrict__ WhT,      // (2048,512) bf16
    const short* __restrict__ Xb,       // (T,B,H) bf16
    const float* __restrict__ bias,     // (2048,)
    unsigned* __restrict__ hbA,         // (B,256) u32 bf16-pairs, parity 0
    unsigned* __restrict__ hbB,         // parity 1
    float* __restrict__ cb,             // (B,H) c carry
    float* __restrict__ out,
    int* __restrict__ cnt) {            // (8,T) counters
  extern __shared__ short whs[];        // 64 gate-cols x 512 k, swizzled (64 KB)

  const int tid = threadIdx.x;
  const int bid = blockIdx.x;
  const int grp = bid >> 5;
  const int j = bid & 31;
  const int rb = grp * 32;
  const int hc0 = j * 16;

  const int wid = tid >> 6;            // 0..1
  const int lane = tid & 63;
  const int lc = lane & 15;
  const int kg = lane >> 4;
  const int rwb = wid * 16;            // wave's row base within group tile
  const int sw = (lc & 7) << 4;

  // ---- WhT slice -> LDS (once, swizzled) ----
  {
    const int lcol = tid >> 1;          // 0..63 gate-col
    const int part = tid & 1;           // 256-short halves
    const int g = lcol >> 4;
    const int gcol = g * 512 + hc0 + (lcol & 15);
    const short* src = WhT + (size_t)gcol * 512 + part * 256;
    const int dbase = lcol * 1024 + part * 512;
    const int swl = (lcol & 7) << 4;
#pragma unroll
    for (int it = 0; it < 32; ++it) {
      short8 v = *(const short8*)(src + it * 8);
      *(short8*)((char*)whs + ((dbase + it * 16) ^ swl)) = v;
    }
  }

  // bias + c state (rows rb+rwb+kg*4+jj, col hc0+lc)
  float breg[4];
#pragma unroll
  for (int g = 0; g < 4; ++g) breg[g] = bias[g * 512 + hc0 + lc];
  float creg[4];
#pragma unroll
  for (int jj = 0; jj < 4; ++jj)
    creg[jj] = cb[(size_t)(rb + rwb + kg * 4 + jj) * HH + hc0 + lc];

  __syncthreads();

  for (int t = 0; t < TT; ++t) {
    // ---- early scalar prefetches ----
    const int rstMine = resets[(size_t)t * BB + rb + rwb + lc];      // A-row mask
    int rstE[4];
#pragma unroll
    for (int jj = 0; jj < 4; ++jj)
      rstE[jj] = resets[(size_t)t * BB + rb + rwb + kg * 4 + jj];

    // ---- X phase: gates += x_t @ Wi (independent of h; fills wait window) ----
    f32x4 acc[4] = {};
    {
      const short* xrow = Xb + ((size_t)t * BB + rb + rwb + lc) * HH;
#pragma unroll
      for (int kk = 0; kk < 16; ++kk) {
        short8 a = *(const short8*)(xrow + kk * 32 + kg * 8);
#pragma unroll
        for (int g = 0; g < 4; ++g) {
          short8 b = *(const short8*)(WiT + (size_t)(g * 512 + hc0 + lc) * 512 +
                                      kk * 32 + kg * 8);
          acc[g] = __builtin_amdgcn_mfma_f32_16x16x32_bf16(a, b, acc[g], 0, 0, 0);
        }
      }
    }

    // ---- poll: previous step fully published? (single word) ----
    if (t > 0) {
      const int* cw = &cnt[grp * TT + (t - 1)];
      while (__hip_atomic_load(cw, __ATOMIC_RELAXED, __HIP_MEMORY_SCOPE_AGENT) < 32)
        __builtin_amdgcn_s_sleep(2);
    }

    // ---- H phase: direct L3 h loads -> in-register mask -> MFMA ----
    {
      const unsigned* hsrc =
          ((t & 1) ? hbB : hbA) + (size_t)(rb + rwb + lc) * 256;
      unsigned hv[64];
#pragma unroll
      for (int kk = 0; kk < 16; ++kk)
#pragma unroll
        for (int w = 0; w < 4; ++w)
          hv[kk * 4 + w] = __hip_atomic_load(&hsrc[kk * 16 + kg * 4 + w],
                                             __ATOMIC_RELAXED,
                                             __HIP_MEMORY_SCOPE_AGENT);
      const bool rm = (rstMine != 0);
#pragma unroll
      for (int kk = 0; kk < 16; ++kk) {
        union { uint4v u; short8 s; } cv;
#pragma unroll
        for (int w = 0; w < 4; ++w) cv.u[w] = rm ? 0u : hv[kk * 4 + w];
        const int kb = kk * 64 + kg * 16;
#pragma unroll
        for (int g = 0; g < 4; ++g) {
          short8 b = *(const short8*)((char*)whs + (((g * 16 + lc) * 1024 + kb) ^ sw));
          acc[g] = __builtin_amdgcn_mfma_f32_16x16x32_bf16(cv.s, b, acc[g], 0, 0, 0);
        }
      }
    }

    // ---- epilogue: in-register cell update ----
    float hn[4];
#pragma unroll
    for (int jj = 0; jj < 4; ++jj) {
      float gi = acc[0][jj] + breg[0];
      float gf = acc[1][jj] + breg[1];
      float gg = acc[2][jj] + breg[2];
      float go = acc[3][jj] + breg[3];
      float cold = rstE[jj] ? 0.f : creg[jj];
      float cn = sigm(gf) * cold + sigm(gi) * tanh_fast(gg);
      hn[jj] = sigm(go) * tanh_fast(cn);
      creg[jj] = cn;
    }

    // ---- publish packed h pairs ----
    float ph[4];
#pragma unroll
    for (int jj = 0; jj < 4; ++jj) ph[jj] = __shfl_xor(hn[jj], 1, 64);
    unsigned* hdst = (t & 1) ? hbA : hbB;
#pragma unroll
    for (int s = 0; s < 2; ++s) {
      const int jj = (lc & 1) * 2 + s;
      unsigned lo16 = (unsigned)(unsigned short)f2bf((lc & 1) ? ph[jj] : hn[jj]);
      unsigned hi16 = (unsigned)(unsigned short)f2bf((lc & 1) ? hn[jj] : ph[jj]);
      size_t widx = (size_t)(rb + rwb + kg * 4 + jj) * 256 + (hc0 >> 1) + (lc >> 1);
      __hip_atomic_store(&hdst[widx], lo16 | (hi16 << 16), __ATOMIC_RELAXED,
                         __HIP_MEMORY_SCOPE_AGENT);
    }
    asm volatile("s_waitcnt vmcnt(0)" ::: "memory");  // h stores acked (this wave)
    __syncthreads();                                  // both waves acked
    if (tid == 0)
      __hip_atomic_fetch_add(&cnt[grp * TT + t], 1, __ATOMIC_RELAXED,
                             __HIP_MEMORY_SCOPE_AGENT);

    // ---- ys / finals: off the critical path ----
    float* ysrow =
        out + (size_t)t * BB * HH + (size_t)(rb + rwb + kg * 4) * HH + hc0 + lc;
#pragma unroll
    for (int jj = 0; jj < 4; ++jj) ysrow[(size_t)jj * HH] = hn[jj];
    if (t == TT - 1) {
#pragma unroll
      for (int jj = 0; jj < 4; ++jj) {
        size_t gidx = (size_t)(rb + rwb + kg * 4 + jj) * HH + hc0 + lc;
        out[(size_t)TT * BB * HH + gidx] = creg[jj];
        out[(size_t)TT * BB * HH + (size_t)BB * HH + gidx] = hn[jj];
      }
    }
  }

  // carry c (deterministic across replays: prep re-inits cb each launch)
#pragma unroll
  for (int jj = 0; jj < 4; ++jj)
    cb[(size_t)(rb + rwb + kg * 4 + jj) * HH + hc0 + lc] = creg[jj];
}

// ---- fallback path (small ws): full-K per-step kernel ----
__global__ __launch_bounds__(64) void lstm_step_fullk(
    const float* __restrict__ xt, const int* __restrict__ rst,
    const float* __restrict__ bias, const short* __restrict__ WiT,
    const short* __restrict__ WhT, const short* __restrict__ hin,
    short* __restrict__ hout, float* __restrict__ cbuf, float* __restrict__ ys) {
  const int lane = threadIdx.x;
  const int lc = lane & 15;
  const int kg = lane >> 4;
  const int r0 = blockIdx.x * 16;
  const int h0 = blockIdx.y * 16;
  const int hc = h0 + lc;

  float coldv[4];
  int rstj[4];
#pragma unroll
  for (int jj = 0; jj < 4; ++jj) {
    int row = r0 + kg * 4 + jj;
    rstj[jj] = rst[row];
    coldv[jj] = cbuf[(size_t)row * HH + hc];
  }

  const int rowA = r0 + lc;
  const bool rm = rst[rowA] != 0;
  const short8 zero = {};
  f32x4 acc[4] = {};
#pragma unroll
  for (int kk = 0; kk < 16; ++kk) {
    const int ko = kk * 32 + kg * 8;
    f32x4 u0 = *(const f32x4*)(xt + (size_t)rowA * HH + ko);
    f32x4 u1 = *(const f32x4*)(xt + (size_t)rowA * HH + ko + 4);
    short8 a;
#pragma unroll
    for (int e = 0; e < 4; ++e) { a[e] = f2bf(u0[e]); a[e + 4] = f2bf(u1[e]); }
#pragma unroll
    for (int g = 0; g < 4; ++g) {
      const short8 b = *(const short8*)(WiT + (size_t)(g * HH + h0 + lc) * HH + ko);
      acc[g] = __builtin_amdgcn_mfma_f32_16x16x32_bf16(a, b, acc[g], 0, 0, 0);
    }
  }
#pragma unroll
  for (int kk = 0; kk < 16; ++kk) {
    const int ko = kk * 32 + kg * 8;
    short8 a = rm ? zero : *(const short8*)(hin + (size_t)rowA * HH + ko);
#pragma unroll
    for (int g = 0; g < 4; ++g) {
      const short8 b = *(const short8*)(WhT + (size_t)(g * HH + h0 + lc) * HH + ko);
      acc[g] = __builtin_amdgcn_mfma_f32_16x16x32_bf16(a, b, acc[g], 0, 0, 0);
    }
  }

#pragma unroll
  for (int jj = 0; jj < 4; ++jj) {
    int row = r0 + kg * 4 + jj;
    float gi = acc[0][jj] + bias[0 * HH + hc];
    float gf = acc[1][jj] + bias[1 * HH + hc];
    float gg = acc[2][jj] + bias[2 * HH + hc];
    float go = acc[3][jj] + bias[3 * HH + hc];
    float cold = rstj[jj] ? 0.f : coldv[jj];
    float cn = sigm(gf) * cold + sigm(gi) * tanh_fast(gg);
    float hn = sigm(go) * tanh_fast(cn);
    cbuf[(size_t)row * HH + hc] = cn;
    hout[(size_t)row * HH + hc] = f2bf(hn);
    ys[(size_t)row * HH + hc] = hn;
  }
}

__global__ void finalize_kernel(const float* __restrict__ cbuf, float* __restrict__ out) {
  int i = blockIdx.x * blockDim.x + threadIdx.x;
  if (i < BB * HH) {
    size_t base = (size_t)TT * BB * HH;
    out[base + i] = cbuf[i];
    out[base + BB * HH + i] = out[(size_t)(TT - 1) * BB * HH + i];
  }
}

extern "C" void kernel_launch(void* const* d_in, const int* in_sizes, int n_in,
                              void* d_out, int out_size, void* d_ws, size_t ws_size,
                              hipStream_t stream) {
  const float* x      = (const float*)d_in[0];
  const int*   resets = (const int*)d_in[1];
  const float* c0     = (const float*)d_in[2];
  const float* h0     = (const float*)d_in[3];
  const float* Wi     = (const float*)d_in[4];
  const float* Wh     = (const float*)d_in[5];
  const float* bias   = (const float*)d_in[6];
  float* out = (float*)d_out;

  char* ws = (char*)d_ws;
  short* WiT = (short*)ws;                                         // 2 MiB
  short* WhT = (short*)(ws + (2u << 20));                          // 2 MiB
  unsigned* hb0 = (unsigned*)(ws + (4u << 20));                    // 256 KiB
  unsigned* hb1 = (unsigned*)(ws + (4u << 20) + (256u << 10));     // 256 KiB
  float* cb  = (float*)(ws + (4u << 20) + (512u << 10));           // 512 KiB
  int*   cnt = (int*)(ws + (5u << 20));                            // 16 KiB
  short* hbf0 = (short*)(ws + (5u << 20) + (64u << 10));           // 256 KiB (fallback)
  short* hbf1 = hbf0 + BB * HH;                                    // 256 KiB (fallback)
  short* Xb  = (short*)(ws + (6u << 20));                          // 128 MiB
  const size_t WS_NEED = (6u << 20) + (size_t)TT * BB * HH * 2;

  prep_kernel<<<2048, 256, 0, stream>>>(Wi, Wh, h0, c0, x, WiT, WhT,
                                        hb0, cb, hbf0, Xb, cnt);

  if (ws_size >= WS_NEED) {
    lstm_fused<<<256, 128, 65536, stream>>>(resets, WiT, WhT, Xb, bias,
                                            hb0, hb1, cb, out, cnt);
  } else {
    for (int t = 0; t < TT; ++t) {
      const short* hin = (t & 1) ? hbf1 : hbf0;
      short* hout      = (t & 1) ? hbf0 : hbf1;
      lstm_step_fullk<<<dim3(16, 32), 64, 0, stream>>>(
          x + (size_t)t * BB * HH, resets + (size_t)t * BB, bias, WiT, WhT,
          hin, hout, cb, out + (size_t)t * BB * HH);
    }
    finalize_kernel<<<(BB * HH + 255) / 256, 256, 0, stream>>>(cb, out);
  }
}

// Round 9
// 5783.696 us; speedup vs baseline: 1.0707x; 1.0707x over previous
//
#include <hip/hip_runtime.h>

#define TT 512
#define BB 256
#define HH 512
#define FH 2048   // 4*H

typedef __attribute__((ext_vector_type(8))) short short8;
typedef __attribute__((ext_vector_type(4))) short short4v;
typedef __attribute__((ext_vector_type(4))) float f32x4;
typedef __attribute__((ext_vector_type(4))) unsigned uint4v;

__device__ __forceinline__ short f2bf(float f) {
  union { float f; unsigned u; } v; v.f = f;
  unsigned r = v.u + 0x7fffu + ((v.u >> 16) & 1u);   // RNE
  return (short)(r >> 16);
}
__device__ __forceinline__ unsigned short f2h(float f) {
  union { _Float16 h; unsigned short u; } v;
  v.h = (_Float16)f;
  return v.u;
}
__device__ __forceinline__ float h2f(unsigned short u) {
  union { _Float16 h; unsigned short u; } v;
  v.u = u;
  return (float)v.h;
}

__device__ __forceinline__ float sigm(float x) {
  return 1.f / (1.f + __expf(-x));
}
__device__ __forceinline__ float tanh_fast(float x) {
  float e = __expf(2.f * x);
  return 1.f - 2.f / (e + 1.f);
}

// prep: weight transposes (bf16 col-major over K=512), X->bf16, packed h init,
// c init, counters zero, fallback h init.
__global__ void prep_kernel(const float* __restrict__ Wi, const float* __restrict__ Wh,
                            const float* __restrict__ h0, const float* __restrict__ c0,
                            const float* __restrict__ x,
                            short* __restrict__ WiT, short* __restrict__ WhT,
                            unsigned* __restrict__ hb0, float* __restrict__ cb,
                            short* __restrict__ hbf, short* __restrict__ Xb,
                            int* __restrict__ cnt) {
  int idx = blockIdx.x * blockDim.x + threadIdx.x;
  int stride = gridDim.x * blockDim.x;
  for (int i = idx; i < FH * HH; i += stride) {
    int col = i >> 9;
    int k = i & 511;
    WiT[i] = f2bf(Wi[(size_t)k * FH + col]);
    WhT[i] = f2bf(Wh[(size_t)k * FH + col]);
  }
  for (int i = idx; i < BB * HH; i += stride) {
    hbf[i] = f2bf(h0[i]);
    cb[i] = c0[i];
  }
  for (int i = idx; i < BB * 256; i += stride) {
    int row = i >> 8;
    int cpx = (i & 255) * 2;
    hb0[i] = (unsigned)(unsigned short)f2bf(h0[(size_t)row * HH + cpx]) |
             ((unsigned)(unsigned short)f2bf(h0[(size_t)row * HH + cpx + 1]) << 16);
  }
  for (int i = idx; i < 8 * TT; i += stride) cnt[i] = 0;
  const size_t nx4 = (size_t)TT * BB * HH / 4;
  for (size_t i = idx; i < nx4; i += stride) {
    f32x4 v = *(const f32x4*)(x + i * 4);
    short4v s = { f2bf(v[0]), f2bf(v[1]), f2bf(v[2]), f2bf(v[3]) };
    *(short4v*)(Xb + i * 4) = s;
  }
}

// 128x128-tile GEMM: Gx16 = fp16(Xb @ WiT^T + bias). Unchanged from R7.
__global__ __launch_bounds__(256) void precomp_kernel(
    const short* __restrict__ Xb, const short* __restrict__ WiT,
    const float* __restrict__ bias, unsigned short* __restrict__ Gx,
    int rowBase) {
  __shared__ short As[128 * 64];
  __shared__ short Bs[128 * 64];

  const int tid = threadIdx.x;
  const int cb0 = blockIdx.x * 128;
  const int rb = blockIdx.y * 128;
  const size_t grow = (size_t)rowBase + rb;

  const int wid = tid >> 6;
  const int lane = tid & 63;
  const int lc = lane & 15;
  const int kg = lane >> 4;
  const int m0 = (wid >> 1) * 64;
  const int n0 = (wid & 1) * 64;

  f32x4 acc[4][4] = {};

  for (int kt = 0; kt < 8; ++kt) {
    const int k0 = kt * 64;
    __syncthreads();
#pragma unroll
    for (int i = 0; i < 4; ++i) {
      const int idx = tid * 4 + i;
      const int row = idx >> 3;
      const int kc = idx & 7;
      short8 av = *(const short8*)(Xb + (grow + row) * 512 + k0 + kc * 8);
      short8 bv = *(const short8*)(WiT + (size_t)(cb0 + row) * 512 + k0 + kc * 8);
      const int off = (row * 128 + kc * 16) ^ ((row & 7) << 4);
      *(short8*)((char*)As + off) = av;
      *(short8*)((char*)Bs + off) = bv;
    }
    __syncthreads();

    const int sw = (lc & 7) << 4;
#pragma unroll
    for (int ks = 0; ks < 2; ++ks) {
      const int kb = ks * 64 + kg * 16;
      short8 af[4], bf[4];
#pragma unroll
      for (int m = 0; m < 4; ++m)
        af[m] = *(const short8*)((char*)As + (((m0 + m * 16 + lc) * 128 + kb) ^ sw));
#pragma unroll
      for (int n = 0; n < 4; ++n)
        bf[n] = *(const short8*)((char*)Bs + (((n0 + n * 16 + lc) * 128 + kb) ^ sw));
#pragma unroll
      for (int m = 0; m < 4; ++m)
#pragma unroll
        for (int n = 0; n < 4; ++n)
          acc[m][n] = __builtin_amdgcn_mfma_f32_16x16x32_bf16(af[m], bf[n],
                                                              acc[m][n], 0, 0, 0);
    }
  }

#pragma unroll
  for (int n = 0; n < 4; ++n) {
    const int col = cb0 + n0 + n * 16 + lc;
    const float bv = bias[col];
#pragma unroll
    for (int m = 0; m < 4; ++m) {
      const int rloc = rb + m0 + m * 16 + kg * 4;
#pragma unroll
      for (int j = 0; j < 4; ++j)
        Gx[(size_t)(rloc + j) * FH + col] = f2h(acc[m][n][j] + bv);
    }
  }
}

// Persistent step kernel: 128 blocks = 8 groups x 16 col-blocks, 256 threads
// (4 waves). Block owns 32 rows x 32 h-cols; wave owns 16 rows x 16 h-cols x
// 4 gates (wave-local epilogue, no LDS exchange). h A-fragments loaded
// DIRECTLY from L3 into registers (batched); Wh slice (128 gate-cols x 512)
// LDS-resident, 128 KB. Sync: one counter word per (group, t); producers
// fetch_add after publish (vmcnt(0) + barrier); consumers poll to ==16.
__global__ __launch_bounds__(256) void lstm_persist(
    const int* __restrict__ resets,         // (T,B)
    const short* __restrict__ WhT,          // (2048,512) bf16
    const unsigned short* __restrict__ Gx,  // (ct,B,2048) fp16, bias included
    unsigned* __restrict__ hbA,             // (B,256) u32 bf16-pairs, parity 0
    unsigned* __restrict__ hbB,             // parity 1
    float* __restrict__ cb,                 // (B,H) c carry
    float* __restrict__ out,
    int* __restrict__ cnt,                  // (8,T) counters
    int t0, int ct) {
  extern __shared__ short whs[];            // 128 gate-cols x 512 k, swizzled (128 KB)

  const int tid = threadIdx.x;
  const int bid = blockIdx.x;
  const int grp = bid >> 4;                 // 0..7
  const int j = bid & 15;                   // col block
  const int rb = grp * 32;
  const int hc0 = j * 32;

  const int wid = tid >> 6;                 // 0..3
  const int lane = tid & 63;
  const int lc = lane & 15;
  const int kg = lane >> 4;
  const int rwb = (wid & 1) * 16;           // wave row base within group tile
  const int hcw = hc0 + (wid >> 1) * 16;    // wave col base (absolute h-col)
  const int sw = (lc & 7) << 4;

  // ---- WhT slice -> LDS (once, swizzled): 128 rows (g*32+hcol) x 512 k ----
  {
    const int lcol = tid >> 1;              // 0..127
    const int part = tid & 1;               // halves of 512 shorts
    const int g = lcol >> 5;
    const int gcol = g * 512 + hc0 + (lcol & 31);
    const short* src = WhT + (size_t)gcol * 512 + part * 256;
    const int dbase = lcol * 1024 + part * 512;
    const int swl = (lcol & 7) << 4;
#pragma unroll
    for (int it = 0; it < 32; ++it) {
      short8 v = *(const short8*)(src + it * 8);
      *(short8*)((char*)whs + ((dbase + it * 16) ^ swl)) = v;
    }
  }

  // c state: rows rb+rwb+kg*4+jj, col hcw+lc
  float creg[4];
#pragma unroll
  for (int jj = 0; jj < 4; ++jj)
    creg[jj] = cb[(size_t)(rb + rwb + kg * 4 + jj) * HH + hcw + lc];

  __syncthreads();

  for (int t = t0; t < t0 + ct; ++t) {
    // ---- early prefetches (latency hides under poll) ----
    const int rstMine = resets[(size_t)t * BB + rb + rwb + lc];     // A-row mask
    int rstE[4];
    float gxv[4][4];
    {
      const unsigned short* gxb = Gx + (size_t)(t - t0) * BB * FH;
#pragma unroll
      for (int jj = 0; jj < 4; ++jj) {
        const int row = rb + rwb + kg * 4 + jj;
        rstE[jj] = resets[(size_t)t * BB + row];
#pragma unroll
        for (int g = 0; g < 4; ++g)
          gxv[g][jj] = h2f(gxb[(size_t)row * FH + g * 512 + hcw + lc]);
      }
    }

    // ---- poll: previous step fully published? (single word, wave 0 only) ----
    if (t > t0) {
      if (wid == 0) {
        const int* cw = &cnt[grp * TT + (t - 1)];
        while (__hip_atomic_load(cw, __ATOMIC_RELAXED, __HIP_MEMORY_SCOPE_AGENT) < 16)
          __builtin_amdgcn_s_sleep(2);
      }
      __syncthreads();
    }

    // ---- H phase: direct L3 h loads (batched) -> MFMA with LDS B ----
    f32x4 acc[4] = {};
    {
      const unsigned* hsrc = ((t & 1) ? hbB : hbA) + (size_t)(rb + rwb + lc) * 256;
      unsigned hv[64];
#pragma unroll
      for (int kk = 0; kk < 16; ++kk)
#pragma unroll
        for (int w = 0; w < 4; ++w)
          hv[kk * 4 + w] = __hip_atomic_load(&hsrc[kk * 16 + kg * 4 + w],
                                             __ATOMIC_RELAXED,
                                             __HIP_MEMORY_SCOPE_AGENT);
      const bool rm = (rstMine != 0);
#pragma unroll
      for (int kk = 0; kk < 16; ++kk) {
        union { uint4v u; short8 s; } cv;
#pragma unroll
        for (int w = 0; w < 4; ++w) cv.u[w] = rm ? 0u : hv[kk * 4 + w];
        const int kb = kk * 64 + kg * 16;
#pragma unroll
        for (int g = 0; g < 4; ++g) {
          const int lcol = g * 32 + (hcw - hc0) + lc;
          short8 b = *(const short8*)((char*)whs + ((lcol * 1024 + kb) ^ sw));
          acc[g] = __builtin_amdgcn_mfma_f32_16x16x32_bf16(cv.s, b, acc[g], 0, 0, 0);
        }
      }
    }

    // ---- epilogue: in-register cell update ----
    float hn[4];
#pragma unroll
    for (int jj = 0; jj < 4; ++jj) {
      float gi = acc[0][jj] + gxv[0][jj];
      float gf = acc[1][jj] + gxv[1][jj];
      float gg = acc[2][jj] + gxv[2][jj];
      float go = acc[3][jj] + gxv[3][jj];
      float cold = rstE[jj] ? 0.f : creg[jj];
      float cn = sigm(gf) * cold + sigm(gi) * tanh_fast(gg);
      hn[jj] = sigm(go) * tanh_fast(cn);
      creg[jj] = cn;
    }

    // ---- publish packed h pairs (lane-pair shuffle; 2 u32 stores/lane) ----
    float ph[4];
#pragma unroll
    for (int jj = 0; jj < 4; ++jj) ph[jj] = __shfl_xor(hn[jj], 1, 64);
    unsigned* hdst = (t & 1) ? hbA : hbB;
#pragma unroll
    for (int s = 0; s < 2; ++s) {
      const int jj = (lc & 1) * 2 + s;
      unsigned lo16 = (unsigned)(unsigned short)f2bf((lc & 1) ? ph[jj] : hn[jj]);
      unsigned hi16 = (unsigned)(unsigned short)f2bf((lc & 1) ? hn[jj] : ph[jj]);
      size_t widx = (size_t)(rb + rwb + kg * 4 + jj) * 256 + (hcw >> 1) + (lc >> 1);
      __hip_atomic_store(&hdst[widx], lo16 | (hi16 << 16), __ATOMIC_RELAXED,
                         __HIP_MEMORY_SCOPE_AGENT);
    }
    asm volatile("s_waitcnt vmcnt(0)" ::: "memory");  // h stores acked (this wave)
    __syncthreads();                                  // all 4 waves acked
    if (tid == 0)
      __hip_atomic_fetch_add(&cnt[grp * TT + t], 1, __ATOMIC_RELAXED,
                             __HIP_MEMORY_SCOPE_AGENT);

    // ---- ys / finals: off the critical path ----
    float* ysrow =
        out + (size_t)t * BB * HH + (size_t)(rb + rwb + kg * 4) * HH + hcw + lc;
#pragma unroll
    for (int jj = 0; jj < 4; ++jj) ysrow[(size_t)jj * HH] = hn[jj];
    if (t == TT - 1) {
#pragma unroll
      for (int jj = 0; jj < 4; ++jj) {
        size_t gidx = (size_t)(rb + rwb + kg * 4 + jj) * HH + hcw + lc;
        out[(size_t)TT * BB * HH + gidx] = creg[jj];
        out[(size_t)TT * BB * HH + (size_t)BB * HH + gidx] = hn[jj];
      }
    }
  }

  // carry c to next chunk / launch
#pragma unroll
  for (int jj = 0; jj < 4; ++jj)
    cb[(size_t)(rb + rwb + kg * 4 + jj) * HH + hcw + lc] = creg[jj];
}

// ---- fallback path (small ws): full-K per-step kernel ----
__global__ __launch_bounds__(64) void lstm_step_fullk(
    const float* __restrict__ xt, const int* __restrict__ rst,
    const float* __restrict__ bias, const short* __restrict__ WiT,
    const short* __restrict__ WhT, const short* __restrict__ hin,
    short* __restrict__ hout, float* __restrict__ cbuf, float* __restrict__ ys) {
  const int lane = threadIdx.x;
  const int lc = lane & 15;
  const int kg = lane >> 4;
  const int r0 = blockIdx.x * 16;
  const int h0 = blockIdx.y * 16;
  const int hc = h0 + lc;

  float coldv[4];
  int rstj[4];
#pragma unroll
  for (int jj = 0; jj < 4; ++jj) {
    int row = r0 + kg * 4 + jj;
    rstj[jj] = rst[row];
    coldv[jj] = cbuf[(size_t)row * HH + hc];
  }

  const int rowA = r0 + lc;
  const bool rm = rst[rowA] != 0;
  const short8 zero = {};
  f32x4 acc[4] = {};
#pragma unroll
  for (int kk = 0; kk < 16; ++kk) {
    const int ko = kk * 32 + kg * 8;
    f32x4 u0 = *(const f32x4*)(xt + (size_t)rowA * HH + ko);
    f32x4 u1 = *(const f32x4*)(xt + (size_t)rowA * HH + ko + 4);
    short8 a;
#pragma unroll
    for (int e = 0; e < 4; ++e) { a[e] = f2bf(u0[e]); a[e + 4] = f2bf(u1[e]); }
#pragma unroll
    for (int g = 0; g < 4; ++g) {
      const short8 b = *(const short8*)(WiT + (size_t)(g * HH + h0 + lc) * HH + ko);
      acc[g] = __builtin_amdgcn_mfma_f32_16x16x32_bf16(a, b, acc[g], 0, 0, 0);
    }
  }
#pragma unroll
  for (int kk = 0; kk < 16; ++kk) {
    const int ko = kk * 32 + kg * 8;
    short8 a = rm ? zero : *(const short8*)(hin + (size_t)rowA * HH + ko);
#pragma unroll
    for (int g = 0; g < 4; ++g) {
      const short8 b = *(const short8*)(WhT + (size_t)(g * HH + h0 + lc) * HH + ko);
      acc[g] = __builtin_amdgcn_mfma_f32_16x16x32_bf16(a, b, acc[g], 0, 0, 0);
    }
  }

#pragma unroll
  for (int jj = 0; jj < 4; ++jj) {
    int row = r0 + kg * 4 + jj;
    float gi = acc[0][jj] + bias[0 * HH + hc];
    float gf = acc[1][jj] + bias[1 * HH + hc];
    float gg = acc[2][jj] + bias[2 * HH + hc];
    float go = acc[3][jj] + bias[3 * HH + hc];
    float cold = rstj[jj] ? 0.f : coldv[jj];
    float cn = sigm(gf) * cold + sigm(gi) * tanh_fast(gg);
    float hn = sigm(go) * tanh_fast(cn);
    cbuf[(size_t)row * HH + hc] = cn;
    hout[(size_t)row * HH + hc] = f2bf(hn);
    ys[(size_t)row * HH + hc] = hn;
  }
}

__global__ void finalize_kernel(const float* __restrict__ cbuf, float* __restrict__ out) {
  int i = blockIdx.x * blockDim.x + threadIdx.x;
  if (i < BB * HH) {
    size_t base = (size_t)TT * BB * HH;
    out[base + i] = cbuf[i];
    out[base + BB * HH + i] = out[(size_t)(TT - 1) * BB * HH + i];
  }
}

extern "C" void kernel_launch(void* const* d_in, const int* in_sizes, int n_in,
                              void* d_out, int out_size, void* d_ws, size_t ws_size,
                              hipStream_t stream) {
  const float* x      = (const float*)d_in[0];
  const int*   resets = (const int*)d_in[1];
  const float* c0     = (const float*)d_in[2];
  const float* h0     = (const float*)d_in[3];
  const float* Wi     = (const float*)d_in[4];
  const float* Wh     = (const float*)d_in[5];
  const float* bias   = (const float*)d_in[6];
  float* out = (float*)d_out;

  char* ws = (char*)d_ws;
  short* WiT = (short*)ws;                                         // 2 MiB
  short* WhT = (short*)(ws + (2u << 20));                          // 2 MiB
  unsigned* hb0 = (unsigned*)(ws + (4u << 20));                    // 256 KiB
  unsigned* hb1 = (unsigned*)(ws + (4u << 20) + (256u << 10));     // 256 KiB
  float* cb  = (float*)(ws + (4u << 20) + (512u << 10));           // 512 KiB
  int*   cnt = (int*)(ws + (5u << 20));                            // 16 KiB
  short* hbf0 = (short*)(ws + (5u << 20) + (64u << 10));           // 256 KiB (fallback)
  short* hbf1 = hbf0 + BB * HH;                                    // 256 KiB (fallback)
  short* Xb  = (short*)(ws + (6u << 20));                          // 128 MiB
  const size_t GX_OFF = (6u << 20) + (size_t)TT * BB * HH * 2;     // 134 MiB
  unsigned short* Gx = (unsigned short*)(ws + GX_OFF);

  const size_t perT = (size_t)BB * FH * 2;                         // 1 MiB/step fp16
  int chunkT = 0;
  if (ws_size > GX_OFF + perT) chunkT = (int)((ws_size - GX_OFF) / perT);
  if (chunkT > TT) chunkT = TT;
  chunkT &= ~1;   // even chunks keep h-buffer parity aligned

  prep_kernel<<<2048, 256, 0, stream>>>(Wi, Wh, h0, c0, x, WiT, WhT,
                                        hb0, cb, hbf0, Xb, cnt);

  if (chunkT >= 2) {
    for (int t0 = 0; t0 < TT; t0 += chunkT) {
      int ct = (TT - t0 < chunkT) ? (TT - t0) : chunkT;
      precomp_kernel<<<dim3(16, ct * 2), 256, 0, stream>>>(Xb, WiT, bias, Gx, t0 * BB);
      lstm_persist<<<128, 256, 131072, stream>>>(resets, WhT, Gx, hb0, hb1,
                                                 cb, out, cnt, t0, ct);
    }
  } else {
    for (int t = 0; t < TT; ++t) {
      const short* hin = (t & 1) ? hbf1 : hbf0;
      short* hout      = (t & 1) ? hbf0 : hbf1;
      lstm_step_fullk<<<dim3(16, 32), 64, 0, stream>>>(
          x + (size_t)t * BB * HH, resets + (size_t)t * BB, bias, WiT, WhT,
          hin, hout, cb, out + (size_t)t * BB * HH);
    }
    finalize_kernel<<<(BB * HH + 255) / 256, 256, 0, stream>>>(cb, out);
  }
}